// Round 10
// baseline (715.341 us; speedup 1.0000x reference)
//
#include <hip/hip_runtime.h>
#include <hip/hip_bf16.h>
#include <math.h>

// B=64, T=256, D=1024, H=4, HID=512, WIN=9, DH=256
enum { M_NONE=0, M_RELU=1, M_GELU=2, M_RESID=3, M_ROWSCALE=4, M_GT=5 };

typedef __hip_bfloat16 bf16;
typedef short s8v __attribute__((ext_vector_type(8)));
typedef short s4v __attribute__((ext_vector_type(4)));
typedef float f4v __attribute__((ext_vector_type(4)));

__device__ __forceinline__ short f2bf(float v) {
  bf16 h = __float2bfloat16(v);
  return *reinterpret_cast<short*>(&h);
}
__device__ __forceinline__ float bf2f(short s) {
  bf16 h = *reinterpret_cast<bf16*>(&s);
  return __bfloat162float(h);
}

// async global->LDS, 16B per lane. LDS dest is wave-uniform base + lane*16 (HW).
__device__ __forceinline__ void gload16(const bf16* g, short* l) {
  __builtin_amdgcn_global_load_lds(
      (const __attribute__((address_space(1))) void*)g,
      (__attribute__((address_space(3))) void*)l, 16, 0, 0);
}

// ============ weight transpose + f32->bf16: dst[(n+rowOff)*dstLd + k] = src[k*N+n] ============
__global__ __launch_bounds__(256)
void transK(const float* __restrict__ src, bf16* __restrict__ dst,
            int N, int rowOff, int dstLd)
{
  __shared__ float tile[32][33];
  int k0 = blockIdx.y * 32, n0 = blockIdx.x * 32;
  int tx = threadIdx.x, ty = threadIdx.y;   // 32 x 8
#pragma unroll
  for (int i = 0; i < 4; i++)
    tile[ty + i * 8][tx] = src[(size_t)(k0 + ty + i * 8) * N + n0 + tx];
  __syncthreads();
#pragma unroll
  for (int i = 0; i < 4; i++)
    dst[(size_t)(n0 + ty + i * 8 + rowOff) * dstLd + k0 + tx] =
        __float2bfloat16(tile[tx][ty + i * 8]);
}

// ============ x f32 -> bf16 ============
__global__ __launch_bounds__(256)
void conv_x(const float* __restrict__ src, bf16* __restrict__ dst, int n4)
{
  for (int i = blockIdx.x * 256 + threadIdx.x; i < n4; i += gridDim.x * 256) {
    float4 v = *(const float4*)&src[(size_t)i * 4];
    dst[(size_t)i * 4 + 0] = __float2bfloat16(v.x);
    dst[(size_t)i * 4 + 1] = __float2bfloat16(v.y);
    dst[(size_t)i * 4 + 2] = __float2bfloat16(v.z);
    dst[(size_t)i * 4 + 3] = __float2bfloat16(v.w);
  }
}

// ============ pack biases ============
__global__ void pack_bias(const float* bq, const float* bk, const float* bv,
                          const float* bg1, const float* bg2,
                          float* bqkv, float* bgg)
{
  int t = blockIdx.x * 256 + threadIdx.x;
  if (t < 512) bqkv[t] = bq[t];
  else if (t < 1024) bqkv[t] = bk[t - 512];
  else if (t < 1536) bqkv[t] = bv[t - 1024];
  else if (t < 1792) bgg[t - 1536] = bg1[t - 1536];
  else if (t < 2048) bgg[t - 1792 + 256] = bg2[t - 1792];
}

// ============ MFMA NT GEMM: C[M x N] = epi(A[M x K] @ Bt[N x K]^T + bias) ============
// 128x128 tile, 4 waves (2x2 of 64x64), 16x16x32 bf16 MFMA, K%32==0.
// Staging via global_load_lds w=16: linear LDS dest; inverse chunk-swizzle on the global src.
// M_GT: C = acc*aux[col] + bias[row]  (transposed-G mode, bf16 out)
template<int MODE, int OUTB>
__global__ __launch_bounds__(256)
void gemm_nt(const bf16* __restrict__ A, const bf16* __restrict__ Bt,
             const float* __restrict__ bias, const float* __restrict__ aux,
             float* __restrict__ Cf, bf16* __restrict__ Cb,
             int K, int ldC, int ldAux)
{
  __shared__ short As[128 * 32];
  __shared__ short Bs[128 * 32];
  const int tid = threadIdx.x;
  const int m0 = blockIdx.y * 128, n0 = blockIdx.x * 128;
  const int w = tid >> 6, l = tid & 63;
  const int wr = w >> 1, wc = w & 1;
  const int lr = l & 15, lk = l >> 4;
  const int srow = l >> 2, sslot = l & 3;   // staging: row-in-segment, chunk slot

  f4v acc[4][4];
#pragma unroll
  for (int m = 0; m < 4; m++)
#pragma unroll
    for (int n = 0; n < 4; n++) acc[m][n] = (f4v){0.f, 0.f, 0.f, 0.f};

  for (int kt = 0; kt < K; kt += 32) {
#pragma unroll
    for (int q = 0; q < 2; q++) {
      int seg = q * 4 + w;                 // 8 segments x 16 rows
      int r = seg * 16 + srow;
      int c = sslot ^ ((r >> 1) & 3);      // inverse swizzle on global chunk
      gload16(&A[(size_t)(m0 + r) * K + kt + c * 8], &As[seg * 512]);
      gload16(&Bt[(size_t)(n0 + r) * K + kt + c * 8], &Bs[seg * 512]);
    }
    __syncthreads();
    s8v af[4], bfr[4];
#pragma unroll
    for (int m = 0; m < 4; m++) {
      int row = wr * 64 + m * 16 + lr;
      af[m] = *(const s8v*)&As[row * 32 + ((lk ^ ((row >> 1) & 3)) * 8)];
      int col = wc * 64 + m * 16 + lr;
      bfr[m] = *(const s8v*)&Bs[col * 32 + ((lk ^ ((col >> 1) & 3)) * 8)];
    }
#pragma unroll
    for (int m = 0; m < 4; m++)
#pragma unroll
      for (int n = 0; n < 4; n++)
        acc[m][n] = __builtin_amdgcn_mfma_f32_16x16x32_bf16(af[m], bfr[n], acc[m][n], 0, 0, 0);
    __syncthreads();
  }

#pragma unroll
  for (int m = 0; m < 4; m++) {
#pragma unroll
    for (int reg = 0; reg < 4; reg++) {
      int grow = m0 + wr * 64 + m * 16 + lk * 4 + reg;
      float rs = (MODE == M_ROWSCALE) ? aux[grow] : 1.f;
      float rb = (MODE == M_GT) ? bias[grow] : 0.f;
#pragma unroll
      for (int n = 0; n < 4; n++) {
        int gcol = n0 + wc * 64 + n * 16 + lr;
        float v = acc[m][n][reg];
        if (MODE == M_GT) {
          v = v * aux[gcol] + rb;
        } else {
          if (MODE == M_ROWSCALE) v *= rs;
          v += bias[gcol];
          if (MODE == M_RELU) v = fmaxf(v, 0.f);
          if (MODE == M_GELU) v = 0.5f * v * (1.f + erff(v * 0.70710678118654752f));
          if (MODE == M_RESID) v += aux[(size_t)grow * ldAux + gcol];
        }
        if (OUTB) Cb[(size_t)grow * ldC + gcol] = __float2bfloat16(v);
        else      Cf[(size_t)grow * ldC + gcol] = v;
      }
    }
  }
}

// ============ batched P @ P^T with Lorentz-threshold epilogue (bf16 thr out) ============
// grid (2,2,64): per b, 128x128 tile of the 256x256 inner-product matrix; K=1024.
__global__ __launch_bounds__(256)
void gemm_pp(const bf16* __restrict__ P, const float* __restrict__ p0,
             bf16* __restrict__ thr)
{
  __shared__ short As[128 * 32];
  __shared__ short Bs[128 * 32];
  const int tid = threadIdx.x;
  const int b = blockIdx.z;
  const int m0 = blockIdx.y * 128, n0 = blockIdx.x * 128;
  const bf16* Pb = P + (size_t)b * 256 * 1024;
  const int w = tid >> 6, l = tid & 63;
  const int wr = w >> 1, wc = w & 1;
  const int lr = l & 15, lk = l >> 4;
  const int srow = l >> 2, sslot = l & 3;

  f4v acc[4][4];
#pragma unroll
  for (int m = 0; m < 4; m++)
#pragma unroll
    for (int n = 0; n < 4; n++) acc[m][n] = (f4v){0.f, 0.f, 0.f, 0.f};

  for (int kt = 0; kt < 1024; kt += 32) {
#pragma unroll
    for (int q = 0; q < 2; q++) {
      int seg = q * 4 + w;
      int r = seg * 16 + srow;
      int c = sslot ^ ((r >> 1) & 3);
      gload16(&Pb[(size_t)(m0 + r) * 1024 + kt + c * 8], &As[seg * 512]);
      gload16(&Pb[(size_t)(n0 + r) * 1024 + kt + c * 8], &Bs[seg * 512]);
    }
    __syncthreads();
    s8v af[4], bfr[4];
#pragma unroll
    for (int m = 0; m < 4; m++) {
      int row = wr * 64 + m * 16 + lr;
      af[m] = *(const s8v*)&As[row * 32 + ((lk ^ ((row >> 1) & 3)) * 8)];
      int col = wc * 64 + m * 16 + lr;
      bfr[m] = *(const s8v*)&Bs[col * 32 + ((lk ^ ((col >> 1) & 3)) * 8)];
    }
#pragma unroll
    for (int m = 0; m < 4; m++)
#pragma unroll
      for (int n = 0; n < 4; n++)
        acc[m][n] = __builtin_amdgcn_mfma_f32_16x16x32_bf16(af[m], bfr[n], acc[m][n], 0, 0, 0);
    __syncthreads();
  }

  const float* p0b = p0 + b * 256;
#pragma unroll
  for (int m = 0; m < 4; m++) {
#pragma unroll
    for (int reg = 0; reg < 4; reg++) {
      int gr = m0 + wr * 64 + m * 16 + lk * 4 + reg;
      float pi = p0b[gr];
#pragma unroll
      for (int n = 0; n < 4; n++) {
        int gc = n0 + wc * 64 + n * 16 + lr;
        float inner = pi * p0b[gc] - acc[m][n][reg];
        float y = fmaxf(inner, 1.f);
        float d = logf(y + sqrtf(fmaxf(y * y - 1.f, 1e-7f)));
        d = fminf(fmaxf(d, 1e-6f), 200.f);
        float a = expf(-d);
        thr[((size_t)(b * 256 + gr)) * 256 + gc] = __float2bfloat16((a > 0.8f) ? a : 0.f);
      }
    }
  }
}

// ============ banded attention (bf16 packed qkv), WIN=9 ============
__global__ __launch_bounds__(256)
void band_attn(const bf16* __restrict__ qkv, const float* __restrict__ wlp,
               const float* __restrict__ blp, bf16* __restrict__ o)
{
  int flat = blockIdx.x * 4 + (threadIdx.x >> 6);  // (b*256+i)*4 + h
  int l = threadIdx.x & 63;
  int h = flat & 3, i = (flat >> 2) & 255, b = flat >> 10;
  const float wl = wlp[0], bl = blp[0];
  size_t rq = ((size_t)(b * 256 + i)) * 1536 + h * 128 + l;
  float q0 = __bfloat162float(qkv[rq]), q1 = __bfloat162float(qkv[rq + 64]);
  float att[9];
#pragma unroll
  for (int jj = 0; jj < 9; jj++) {
    int j = i - 4 + jj;
    float val = -1e30f;
    if (j >= 0 && j < 256) {
      size_t rk = ((size_t)(b * 256 + j)) * 1536 + h * 128 + l + 512;
      float p = q0 * __bfloat162float(qkv[rk]) + q1 * __bfloat162float(qkv[rk + 64]);
#pragma unroll
      for (int s = 32; s; s >>= 1) p += __shfl_xor(p, s);
      float dd = fabsf((float)(i - j));
      float adj = expf(-fabsf(wl * dd * dd - bl));
      val = p * 0.03125f + adj;   // 1/sqrt(1024)
    }
    att[jj] = val;
  }
  float m = att[0];
#pragma unroll
  for (int jj = 1; jj < 9; jj++) m = fmaxf(m, att[jj]);
  float p[9], sum = 0.f;
#pragma unroll
  for (int jj = 0; jj < 9; jj++) { p[jj] = expf(att[jj] - m); sum += p[jj]; }
  float inv = 1.f / sum;
  float o0 = 0.f, o1 = 0.f;
#pragma unroll
  for (int jj = 0; jj < 9; jj++) {
    int j = i - 4 + jj;
    if (j >= 0 && j < 256) {
      size_t rv = ((size_t)(b * 256 + j)) * 1536 + h * 128 + l + 1024;
      float wgt = p[jj] * inv;
      o0 += wgt * __bfloat162float(qkv[rv]);
      o1 += wgt * __bfloat162float(qkv[rv + 64]);
    }
  }
  size_t ro = ((size_t)(b * 256 + i)) * 512 + h * 128 + l;
  o[ro] = __float2bfloat16(o0);
  o[ro + 64] = __float2bfloat16(o1);
}

// ============ row norm + expmap0 -> Pb bf16, p0, alpha ============
__global__ __launch_bounds__(256)
void rownorm_proj(const float* __restrict__ xcat, const float* __restrict__ cx,
                  bf16* __restrict__ Pb, float* __restrict__ p0,
                  float* __restrict__ alpha)
{
  int row = blockIdx.x;
  int t = threadIdx.x;
  float4 e;
  if (t < 128) e = *(const float4*)&xcat[(size_t)row * 512 + t * 4];
  else         e = *(const float4*)&cx[(size_t)row * 512 + (t - 128) * 4];
  float s = e.x * e.x + e.y * e.y + e.z * e.z + e.w * e.w;
#pragma unroll
  for (int o = 32; o; o >>= 1) s += __shfl_xor(s, o);
  __shared__ float red[4];
  if ((t & 63) == 0) red[t >> 6] = s;
  __syncthreads();
  float tot = red[0] + red[1] + red[2] + red[3];
  float n = fmaxf(sqrtf(tot), 1e-7f);
  float ch = coshf(n), sh = sinhf(n);
  float sc = sh / n;
  float4 pr; pr.x = sc * e.x; pr.y = sc * e.y; pr.z = sc * e.z; pr.w = sc * e.w;
  size_t po = (size_t)row * 1024 + t * 4;
  Pb[po + 0] = __float2bfloat16(pr.x);
  Pb[po + 1] = __float2bfloat16(pr.y);
  Pb[po + 2] = __float2bfloat16(pr.z);
  Pb[po + 3] = __float2bfloat16(pr.w);
  float s2 = pr.x * pr.x + pr.y * pr.y + pr.z * pr.z + pr.w * pr.w;
#pragma unroll
  for (int o = 32; o; o >>= 1) s2 += __shfl_xor(s2, o);
  __syncthreads();
  if ((t & 63) == 0) red[t >> 6] = s2;
  __syncthreads();
  float tot2 = red[0] + red[1] + red[2] + red[3];
  if (t == 0) {
    float ns = fmaxf(sqrtf(tot2), 1e-7f);
    float y0 = fmaxf(ch, 1.f + 1e-7f);
    float d = logf(y0 + sqrtf(y0 * y0 - 1.f));
    p0[row] = ch;
    alpha[row] = d / ns;
  }
}

// ============ softmax(thr bf16) + MFMA { S@G1t , disadj@G2t } -> xc f32 ============
// grid (8, 64) = (i-tiles of 32, b). 256 thr = 4 waves; per pass wave w owns n-slice w*64..+64.
// Gt: bf16 [512][16384], row n = output feature (0..255 = G1, 256..511 = G2), col = b*256+j.
__global__ __launch_bounds__(256)
void adj_apply(const bf16* __restrict__ thr, const bf16* __restrict__ Gt,
               const int* __restrict__ seq_len, float* __restrict__ xc)
{
  __shared__ short Sb[32 * 264];        // S bf16, row stride 264 (pad 8 -> 2-way banks)
  __shared__ short Bst[4 * 256 * 8];    // k-major B tile: [kc][n][8]
  const int tid = threadIdx.x;
  const int ty = tid >> 4, tx = tid & 15;
  const int i0 = blockIdx.x * 32;
  const int b  = blockIdx.y;
  const int sl = seq_len[b];
  const int w = tid >> 6, l = tid & 63;
  const int lr = l & 15, lk = l >> 4;
  const float INV_E = 0.36787944117144233f;

  // ---- load thr rows (bf16), masked softmax in f32 (same math as before) ----
  float acc[2][16];
#pragma unroll
  for (int r = 0; r < 2; r++) {
    const short* trow = (const short*)(thr + ((size_t)(b * 256 + i0 + ty * 2 + r)) * 256);
#pragma unroll
    for (int m = 0; m < 4; m++) {
      s4v t4 = *(const s4v*)&trow[m * 64 + tx * 4];
      acc[r][m*4+0] = bf2f(t4[0]); acc[r][m*4+1] = bf2f(t4[1]);
      acc[r][m*4+2] = bf2f(t4[2]); acc[r][m*4+3] = bf2f(t4[3]);
    }
  }
  float mx[2] = {-1e30f, -1e30f};
#pragma unroll
  for (int r = 0; r < 2; r++)
#pragma unroll
    for (int m = 0; m < 4; m++)
#pragma unroll
      for (int q = 0; q < 4; q++) {
        int idx = m * 4 + q;
        int c = m * 64 + tx * 4 + q;
        float lg = (c < sl) ? acc[r][idx] : -1e30f;
        acc[r][idx] = lg;
        mx[r] = fmaxf(mx[r], lg);
      }
#pragma unroll
  for (int o = 1; o < 16; o <<= 1) {
    mx[0] = fmaxf(mx[0], __shfl_xor(mx[0], o));
    mx[1] = fmaxf(mx[1], __shfl_xor(mx[1], o));
  }
  float sm[2] = {0.f, 0.f};
#pragma unroll
  for (int r = 0; r < 2; r++)
#pragma unroll
    for (int idx = 0; idx < 16; idx++) {
      float e = (acc[r][idx] > -1e29f) ? expf(acc[r][idx] - mx[r]) : 0.f;
      acc[r][idx] = e; sm[r] += e;
    }
#pragma unroll
  for (int o = 1; o < 16; o <<= 1) {
    sm[0] += __shfl_xor(sm[0], o);
    sm[1] += __shfl_xor(sm[1], o);
  }
  float inv[2] = {1.f / sm[0], 1.f / sm[1]};
  bool vi[2] = { (i0 + ty * 2) < sl, (i0 + ty * 2 + 1) < sl };
  // S -> LDS bf16 (zero rows for invalid i)
#pragma unroll
  for (int r = 0; r < 2; r++)
#pragma unroll
    for (int m = 0; m < 4; m++) {
      s4v s4;
#pragma unroll
      for (int q = 0; q < 4; q++)
        s4[q] = f2bf(vi[r] ? acc[r][m*4+q] * inv[r] : 0.f);
      *(s4v*)&Sb[(ty * 2 + r) * 264 + m * 64 + tx * 4] = s4;
    }
  __syncthreads();

  // ---- two MFMA passes over K=256 (j) ----
  for (int pass = 0; pass < 2; ++pass) {
    const int nOff = pass * 256;
    f4v a2[2][4];
#pragma unroll
    for (int m = 0; m < 2; m++)
#pragma unroll
      for (int n = 0; n < 4; n++) a2[m][n] = (f4v){0.f, 0.f, 0.f, 0.f};

    for (int kt = 0; kt < 256; kt += 32) {
      // stage B tile [256 n][32 k] -> k-major LDS [kc][n][8]; thread tid = row n, rep = kc
      s8v breg[4];
      const size_t gbase = (size_t)(nOff + tid) * 16384 + b * 256 + kt;
#pragma unroll
      for (int rch = 0; rch < 4; rch++)
        breg[rch] = *(const s8v*)&((const short*)Gt)[gbase + rch * 8];
      __syncthreads();   // previous K-step reads done
#pragma unroll
      for (int rch = 0; rch < 4; rch++)
        *(s8v*)&Bst[rch * 2048 + tid * 8] = breg[rch];
      __syncthreads();

      s8v af[2], bfr[4];
#pragma unroll
      for (int m = 0; m < 2; m++) {
        if (pass == 0) {
          af[m] = *(const s8v*)&Sb[(m * 16 + lr) * 264 + kt + lk * 8];
        } else {
          float ri = (float)(i0 + m * 16 + lr);
#pragma unroll
          for (int e = 0; e < 8; e++) {
            float jv = (float)(kt + lk * 8 + e);
            af[m][e] = f2bf(__expf(-fabsf(ri - jv) * INV_E));
          }
        }
      }
#pragma unroll
      for (int n = 0; n < 4; n++)
        bfr[n] = *(const s8v*)&Bst[lk * 2048 + (w * 64 + n * 16 + lr) * 8];
#pragma unroll
      for (int m = 0; m < 2; m++)
#pragma unroll
        for (int n = 0; n < 4; n++)
          a2[m][n] = __builtin_amdgcn_mfma_f32_16x16x32_bf16(af[m], bfr[n], a2[m][n], 0, 0, 0);
    }

    // epilogue: leaky_relu -> xc f32
#pragma unroll
    for (int m = 0; m < 2; m++)
#pragma unroll
      for (int reg = 0; reg < 4; reg++) {
        size_t grow = (size_t)(b * 256 + i0 + m * 16 + lk * 4 + reg);
#pragma unroll
        for (int n = 0; n < 4; n++) {
          int gcol = nOff + w * 64 + n * 16 + lr;
          float v = a2[m][n][reg];
          v = v > 0.f ? v : 0.01f * v;
          xc[grow * 512 + gcol] = v;
        }
      }
    __syncthreads();  // Bst reuse across passes
  }
}

// ============ LayerNorm over 512, bf16 out ============
__global__ __launch_bounds__(256)
void layernorm_k(const float* __restrict__ xc, const float* __restrict__ g,
                 const float* __restrict__ bta, bf16* __restrict__ out)
{
  int row = blockIdx.x * 4 + (threadIdx.x >> 6);
  int l = threadIdx.x & 63;
  const float* r = xc + (size_t)row * 512;
  float v[8];
  float s = 0.f;
#pragma unroll
  for (int q = 0; q < 8; q++) { v[q] = r[l + 64 * q]; s += v[q]; }
#pragma unroll
  for (int o = 32; o; o >>= 1) s += __shfl_xor(s, o);
  float mu = s * (1.f / 512.f);
  float s2 = 0.f;
#pragma unroll
  for (int q = 0; q < 8; q++) { float d = v[q] - mu; s2 += d * d; }
#pragma unroll
  for (int o = 32; o; o >>= 1) s2 += __shfl_xor(s2, o);
  float var = s2 * (1.f / 512.f);
  float inv = 1.f / sqrtf(var + 1e-5f);
#pragma unroll
  for (int q = 0; q < 8; q++) {
    int c = l + 64 * q;
    out[(size_t)row * 512 + c] = __float2bfloat16((v[q] - mu) * inv * g[c] + bta[c]);
  }
}

// ============ x_e = sigmoid(xt @ Wcls + bcls) ============
__global__ __launch_bounds__(256)
void xe_kernel(const float* __restrict__ xt, const float* __restrict__ Wcls,
               const float* __restrict__ bcls, float* __restrict__ out)
{
  int row = blockIdx.x * 4 + (threadIdx.x >> 6);
  int l = threadIdx.x & 63;
  float s = 0.f;
#pragma unroll
  for (int q = 0; q < 8; q++) {
    int c = l + 64 * q;
    s += xt[(size_t)row * 512 + c] * Wcls[c];
  }
#pragma unroll
  for (int o = 32; o; o >>= 1) s += __shfl_xor(s, o);
  if (l == 0) out[row] = 1.f / (1.f + expf(-(s + bcls[0])));
}

// ============ transpose xt (B,T,512) -> (B,512,T) ============
__global__ void transpose_xt(const float* __restrict__ xt, float* __restrict__ out)
{
  __shared__ float tile[32][33];
  int b = blockIdx.z;
  int t0 = blockIdx.x * 32, d0 = blockIdx.y * 32;
  int tx = threadIdx.x, ty = threadIdx.y;   // 32 x 8
#pragma unroll
  for (int i = 0; i < 4; i++)
    tile[ty + i * 8][tx] = xt[((size_t)(b * 256) + t0 + ty + i * 8) * 512 + d0 + tx];
  __syncthreads();
#pragma unroll
  for (int i = 0; i < 4; i++)
    out[((size_t)(b * 512) + d0 + ty + i * 8) * 256 + t0 + tx] = tile[tx][ty + i * 8];
}

// ============ launch ============
extern "C" void kernel_launch(void* const* d_in, const int* in_sizes, int n_in,
                              void* d_out, int out_size, void* d_ws, size_t ws_size,
                              hipStream_t stream) {
  (void)in_sizes; (void)n_in; (void)out_size; (void)ws_size;
  const float* x     = (const float*)d_in[0];
  const float* c_x   = (const float*)d_in[1];
  const float* w_loc = (const float*)d_in[2];
  const float* b_loc = (const float*)d_in[3];
  const float* Wq    = (const float*)d_in[4];
  const float* bq    = (const float*)d_in[5];
  const float* Wk    = (const float*)d_in[6];
  const float* bk    = (const float*)d_in[7];
  const float* Wv    = (const float*)d_in[8];
  const float* bv    = (const float*)d_in[9];
  const float* Wo    = (const float*)d_in[10];
  const float* bo    = (const float*)d_in[11];
  const float* Wc1   = (const float*)d_in[12];
  const float* bc1   = (const float*)d_in[13];
  const float* Wg1   = (const float*)d_in[14];
  const float* bg1   = (const float*)d_in[15];
  const float* Wg2   = (const float*)d_in[16];
  const float* bg2   = (const float*)d_in[17];
  const float* ln_g  = (const float*)d_in[18];
  const float* ln_b  = (const float*)d_in[19];
  const float* Wl1   = (const float*)d_in[20];
  const float* bl1   = (const float*)d_in[21];
  const float* Wcls  = (const float*)d_in[22];
  const float* bcls  = (const float*)d_in[23];
  const int*   seq_len = (const int*)d_in[24];

  float* ws = (float*)d_ws;
  // region A [0, 8388608): xb -> x2b -> Gt(bf16) -> xnb
  bf16*  xb    = (bf16*)ws;                       // 16384x1024 bf16
  bf16*  x2b   = (bf16*)ws;                       // 16384x1024 bf16
  bf16*  Gtb   = (bf16*)ws;                       // 512x16384 bf16 (16MB)
  bf16*  xnb   = (bf16*)ws;                       // 16384x512 bf16
  // region B [8388608, 25165824): qkvb -> (xcat, Pb)
  bf16*  qkvb  = (bf16*)(ws + 8388608);           // 16384x1536 bf16
  float* xcat  = ws + 8388608;                    // 16384x512 f32
  bf16*  Pb    = (bf16*)(ws + 16777216);          // 16384x1024 bf16
  // region C [25165824, 33554432): thr(bf16) -> xt(f32)
  bf16*  thrb  = (bf16*)(ws + 25165824);          // 16384x256 bf16 (8MB)
  float* xt    = ws + 25165824;                   // 16384x512 f32
  // region E [33554432, 37748736): ob
  bf16*  ob    = (bf16*)(ws + 33554432);          // 16384x512 bf16
  // region F [37748736, 46137344): xc
  float* xc    = ws + 37748736;                   // 16384x512 f32
  // region G [46137344, ...): weights + scalars
  bf16*  WqkvT = (bf16*)(ws + 46137344);          // 1536x1024
  bf16*  WoT   = (bf16*)(ws + 46923776);          // 1024x512
  bf16*  Wc1T  = (bf16*)(ws + 47185920);          // 512x1024
  bf16*  Wg12T = (bf16*)(ws + 47448064);          // 512x1024
  bf16*  Wl1T  = (bf16*)(ws + 47710208);          // 512x512
  float* bqkv  = ws + 47841280;                   // 1536
  float* bgg   = ws + 47842816;                   // 512
  float* p0    = ws + 47843328;                   // 16384
  float* alpha = ws + 47859712;                   // 16384

  dim3 blk(256);
  dim3 tblk(32, 8);
  // weight packs (bf16, transposed to NT layout)
  transK<<<dim3(16, 32), tblk, 0, stream>>>(Wq,  WqkvT, 512,    0, 1024);
  transK<<<dim3(16, 32), tblk, 0, stream>>>(Wk,  WqkvT, 512,  512, 1024);
  transK<<<dim3(16, 32), tblk, 0, stream>>>(Wv,  WqkvT, 512, 1024, 1024);
  transK<<<dim3(32, 16), tblk, 0, stream>>>(Wo,  WoT, 1024,    0,  512);
  transK<<<dim3(16, 32), tblk, 0, stream>>>(Wc1, Wc1T, 512,    0, 1024);
  transK<<<dim3( 8, 32), tblk, 0, stream>>>(Wg1, Wg12T, 256,   0, 1024);
  transK<<<dim3( 8, 32), tblk, 0, stream>>>(Wg2, Wg12T, 256, 256, 1024);
  transK<<<dim3(16, 16), tblk, 0, stream>>>(Wl1, Wl1T, 512,    0,  512);
  conv_x<<<2048, blk, 0, stream>>>(x, xb, 4194304);
  pack_bias<<<8, blk, 0, stream>>>(bq, bk, bv, bg1, bg2, bqkv, bgg);

  // qkv = x @ [Wq|Wk|Wv] + b  (bf16 out, packed N=1536)
  gemm_nt<M_NONE, 1><<<dim3(12, 128), blk, 0, stream>>>(xb, WqkvT, bqkv, nullptr, nullptr, qkvb, 1024, 1536, 0);
  // banded attention
  band_attn<<<16384, blk, 0, stream>>>(qkvb, w_loc, b_loc, ob);
  // x2 = x + o@Wo + bo (bf16 out)
  gemm_nt<M_RESID, 1><<<dim3(8, 128), blk, 0, stream>>>(ob, WoT, bo, x, nullptr, x2b, 512, 1024, 1024);
  // xcat = relu(x2@Wc1 + bc1) (f32 out)
  gemm_nt<M_RELU, 0><<<dim3(4, 128), blk, 0, stream>>>(x2b, Wc1T, bc1, nullptr, xcat, nullptr, 1024, 512, 0);
  // expmap0 -> Pb bf16, p0, alpha
  rownorm_proj<<<16384, blk, 0, stream>>>(xcat, c_x, Pb, p0, alpha);
  // Gt[n][b*256+j] = alpha[j] * (Wg12T @ Pb^T) + bgg[n]  (bf16, transposed-G for MFMA B-operand)
  gemm_nt<M_GT, 1><<<dim3(128, 4), blk, 0, stream>>>(Wg12T, Pb, bgg, alpha, nullptr, Gtb, 1024, 16384, 0);
  // thr = lorentz threshold of P@P^T (bf16 out)
  gemm_pp<<<dim3(2, 2, 64), blk, 0, stream>>>(Pb, p0, thrb);
  // softmax + MFMA S@G1t + disadj@G2t
  adj_apply<<<dim3(8, 64), blk, 0, stream>>>(thrb, Gtb, seq_len, xc);
  // LayerNorm (bf16 out)
  layernorm_k<<<4096, blk, 0, stream>>>(xc, ln_g, ln_b, xnb);
  // xt = gelu(xn@Wl1 + bl1) (f32 out)
  gemm_nt<M_GELU, 0><<<dim3(4, 128), blk, 0, stream>>>(xnb, Wl1T, bl1, nullptr, xt, nullptr, 512, 512, 0);
  // outputs
  float* out = (float*)d_out;
  xe_kernel<<<4096, blk, 0, stream>>>(xt, Wcls, bcls, out);
  transpose_xt<<<dim3(8, 16, 64), tblk, 0, stream>>>(xt, out + 16384);
}

// Round 12
// 646.146 us; speedup vs baseline: 1.1071x; 1.1071x over previous
//
#include <hip/hip_runtime.h>
#include <hip/hip_bf16.h>
#include <math.h>

// B=64, T=256, D=1024, H=4, HID=512, WIN=9, DH=256
enum { M_NONE=0, M_RELU=1, M_GELU=2, M_RESID=3, M_ROWSCALE=4 };

typedef __hip_bfloat16 bf16;
typedef short s8v __attribute__((ext_vector_type(8)));
typedef float f4v __attribute__((ext_vector_type(4)));

// async global->LDS, 16B per lane. LDS dest is wave-uniform base + lane*16 (HW).
__device__ __forceinline__ void gload16(const bf16* g, short* l) {
  __builtin_amdgcn_global_load_lds(
      (const __attribute__((address_space(1))) void*)g,
      (__attribute__((address_space(3))) void*)l, 16, 0, 0);
}

// ============ weight transpose + f32->bf16: dst[(n+rowOff)*dstLd + k] = src[k*N+n] ============
__global__ __launch_bounds__(256)
void transK(const float* __restrict__ src, bf16* __restrict__ dst,
            int N, int rowOff, int dstLd)
{
  __shared__ float tile[32][33];
  int k0 = blockIdx.y * 32, n0 = blockIdx.x * 32;
  int tx = threadIdx.x, ty = threadIdx.y;   // 32 x 8
#pragma unroll
  for (int i = 0; i < 4; i++)
    tile[ty + i * 8][tx] = src[(size_t)(k0 + ty + i * 8) * N + n0 + tx];
  __syncthreads();
#pragma unroll
  for (int i = 0; i < 4; i++)
    dst[(size_t)(n0 + ty + i * 8 + rowOff) * dstLd + k0 + tx] =
        __float2bfloat16(tile[tx][ty + i * 8]);
}

// ============ x f32 -> bf16 ============
__global__ __launch_bounds__(256)
void conv_x(const float* __restrict__ src, bf16* __restrict__ dst, int n4)
{
  for (int i = blockIdx.x * 256 + threadIdx.x; i < n4; i += gridDim.x * 256) {
    float4 v = *(const float4*)&src[(size_t)i * 4];
    dst[(size_t)i * 4 + 0] = __float2bfloat16(v.x);
    dst[(size_t)i * 4 + 1] = __float2bfloat16(v.y);
    dst[(size_t)i * 4 + 2] = __float2bfloat16(v.z);
    dst[(size_t)i * 4 + 3] = __float2bfloat16(v.w);
  }
}

// ============ pack biases ============
__global__ void pack_bias(const float* bq, const float* bk, const float* bv,
                          const float* bg1, const float* bg2,
                          float* bqkv, float* bgg)
{
  int t = blockIdx.x * 256 + threadIdx.x;
  if (t < 512) bqkv[t] = bq[t];
  else if (t < 1024) bqkv[t] = bk[t - 512];
  else if (t < 1536) bqkv[t] = bv[t - 1024];
  else if (t < 1792) bgg[t - 1536] = bg1[t - 1536];
  else if (t < 2048) bgg[t - 1792 + 256] = bg2[t - 1792];
}

// ============ MFMA NT GEMM: C[M x N] = epi(A[M x K] @ Bt[N x K]^T + bias) ============
// 128x128 tile, 4 waves (2x2 of 64x64), 16x16x32 bf16 MFMA, K%64==0.
// 2-phase double-buffered pipeline (T3 minimum): issue next tile's global_load_lds
// BEFORE computing the current tile; one __syncthreads (vmcnt drain) per tile.
// Static LDS buffers (no dynamic indexing). Inverse chunk-swizzle on global src.
template<int MODE, int OUTB>
__global__ __launch_bounds__(256)
void gemm_nt(const bf16* __restrict__ A, const bf16* __restrict__ Bt,
             const float* __restrict__ bias, const float* __restrict__ aux,
             float* __restrict__ Cf, bf16* __restrict__ Cb,
             int K, int ldC, int ldAux)
{
  __shared__ short As0[128 * 32], Bs0[128 * 32];
  __shared__ short As1[128 * 32], Bs1[128 * 32];
  const int tid = threadIdx.x;
  const int m0 = blockIdx.y * 128, n0 = blockIdx.x * 128;
  const int w = tid >> 6, l = tid & 63;
  const int wr = w >> 1, wc = w & 1;
  const int lr = l & 15, lk = l >> 4;
  const int srow = l >> 2, sslot = l & 3;   // staging: row-in-segment, chunk slot

  f4v acc[4][4];
#pragma unroll
  for (int m = 0; m < 4; m++)
#pragma unroll
    for (int n = 0; n < 4; n++) acc[m][n] = (f4v){0.f, 0.f, 0.f, 0.f};

  auto STAGE = [&](short* Asb, short* Bsb, int kt) {
#pragma unroll
    for (int q = 0; q < 2; q++) {
      int seg = q * 4 + w;                 // 8 segments x 16 rows
      int r = seg * 16 + srow;
      int c = sslot ^ ((r >> 1) & 3);      // inverse swizzle on global chunk
      gload16(&A[(size_t)(m0 + r) * K + kt + c * 8], &Asb[seg * 512]);
      gload16(&Bt[(size_t)(n0 + r) * K + kt + c * 8], &Bsb[seg * 512]);
    }
  };
  auto COMPUTE = [&](const short* Asb, const short* Bsb) {
    s8v af[4], bfr[4];
#pragma unroll
    for (int m = 0; m < 4; m++) {
      int row = wr * 64 + m * 16 + lr;
      af[m] = *(const s8v*)&Asb[row * 32 + ((lk ^ ((row >> 1) & 3)) * 8)];
      int col = wc * 64 + m * 16 + lr;
      bfr[m] = *(const s8v*)&Bsb[col * 32 + ((lk ^ ((col >> 1) & 3)) * 8)];
    }
#pragma unroll
    for (int m = 0; m < 4; m++)
#pragma unroll
      for (int n = 0; n < 4; n++)
        acc[m][n] = __builtin_amdgcn_mfma_f32_16x16x32_bf16(af[m], bfr[n], acc[m][n], 0, 0, 0);
  };

  STAGE(As0, Bs0, 0);
  __syncthreads();
  for (int kt = 0; kt < K; kt += 64) {
    if (kt + 32 < K) STAGE(As1, Bs1, kt + 32);
    COMPUTE(As0, Bs0);
    __syncthreads();
    if (kt + 64 < K) STAGE(As0, Bs0, kt + 64);
    if (kt + 32 < K) COMPUTE(As1, Bs1);
    __syncthreads();
  }

#pragma unroll
  for (int m = 0; m < 4; m++) {
#pragma unroll
    for (int reg = 0; reg < 4; reg++) {
      int grow = m0 + wr * 64 + m * 16 + lk * 4 + reg;
      float rs = (MODE == M_ROWSCALE) ? aux[grow] : 1.f;
#pragma unroll
      for (int n = 0; n < 4; n++) {
        int gcol = n0 + wc * 64 + n * 16 + lr;
        float v = acc[m][n][reg];
        if (MODE == M_ROWSCALE) v *= rs;
        v += bias[gcol];
        if (MODE == M_RELU) v = fmaxf(v, 0.f);
        if (MODE == M_GELU) v = 0.5f * v * (1.f + erff(v * 0.70710678118654752f));
        if (MODE == M_RESID) v += aux[(size_t)grow * ldAux + gcol];
        if (OUTB) Cb[(size_t)grow * ldC + gcol] = __float2bfloat16(v);
        else      Cf[(size_t)grow * ldC + gcol] = v;
      }
    }
  }
}

// ============ batched P @ P^T with Lorentz-threshold epilogue ============
// grid (2,2,64): per b, 128x128 tile of the 256x256 inner-product matrix; K=1024.
// Same 2-phase pipeline as gemm_nt.
__global__ __launch_bounds__(256)
void gemm_pp(const bf16* __restrict__ P, const float* __restrict__ p0,
             float* __restrict__ thr)
{
  __shared__ short As0[128 * 32], Bs0[128 * 32];
  __shared__ short As1[128 * 32], Bs1[128 * 32];
  const int tid = threadIdx.x;
  const int b = blockIdx.z;
  const int m0 = blockIdx.y * 128, n0 = blockIdx.x * 128;
  const bf16* Pb = P + (size_t)b * 256 * 1024;
  const int w = tid >> 6, l = tid & 63;
  const int wr = w >> 1, wc = w & 1;
  const int lr = l & 15, lk = l >> 4;
  const int srow = l >> 2, sslot = l & 3;

  f4v acc[4][4];
#pragma unroll
  for (int m = 0; m < 4; m++)
#pragma unroll
    for (int n = 0; n < 4; n++) acc[m][n] = (f4v){0.f, 0.f, 0.f, 0.f};

  auto STAGE = [&](short* Asb, short* Bsb, int kt) {
#pragma unroll
    for (int q = 0; q < 2; q++) {
      int seg = q * 4 + w;
      int r = seg * 16 + srow;
      int c = sslot ^ ((r >> 1) & 3);
      gload16(&Pb[(size_t)(m0 + r) * 1024 + kt + c * 8], &Asb[seg * 512]);
      gload16(&Pb[(size_t)(n0 + r) * 1024 + kt + c * 8], &Bsb[seg * 512]);
    }
  };
  auto COMPUTE = [&](const short* Asb, const short* Bsb) {
    s8v af[4], bfr[4];
#pragma unroll
    for (int m = 0; m < 4; m++) {
      int row = wr * 64 + m * 16 + lr;
      af[m] = *(const s8v*)&Asb[row * 32 + ((lk ^ ((row >> 1) & 3)) * 8)];
      int col = wc * 64 + m * 16 + lr;
      bfr[m] = *(const s8v*)&Bsb[col * 32 + ((lk ^ ((col >> 1) & 3)) * 8)];
    }
#pragma unroll
    for (int m = 0; m < 4; m++)
#pragma unroll
      for (int n = 0; n < 4; n++)
        acc[m][n] = __builtin_amdgcn_mfma_f32_16x16x32_bf16(af[m], bfr[n], acc[m][n], 0, 0, 0);
  };

  STAGE(As0, Bs0, 0);
  __syncthreads();
  for (int kt = 0; kt < 1024; kt += 64) {
    if (kt + 32 < 1024) STAGE(As1, Bs1, kt + 32);
    COMPUTE(As0, Bs0);
    __syncthreads();
    if (kt + 64 < 1024) STAGE(As0, Bs0, kt + 64);
    if (kt + 32 < 1024) COMPUTE(As1, Bs1);
    __syncthreads();
  }

  const float* p0b = p0 + b * 256;
#pragma unroll
  for (int m = 0; m < 4; m++) {
#pragma unroll
    for (int reg = 0; reg < 4; reg++) {
      int gr = m0 + wr * 64 + m * 16 + lk * 4 + reg;
      float pi = p0b[gr];
#pragma unroll
      for (int n = 0; n < 4; n++) {
        int gc = n0 + wc * 64 + n * 16 + lr;
        float inner = pi * p0b[gc] - acc[m][n][reg];
        float y = fmaxf(inner, 1.f);
        float d = logf(y + sqrtf(fmaxf(y * y - 1.f, 1e-7f)));
        d = fminf(fmaxf(d, 1e-6f), 200.f);
        float a = expf(-d);
        thr[((size_t)(b * 256 + gr)) * 256 + gc] = (a > 0.8f) ? a : 0.f;
      }
    }
  }
}

// ============ banded attention (bf16 packed qkv), WIN=9 ============
__global__ __launch_bounds__(256)
void band_attn(const bf16* __restrict__ qkv, const float* __restrict__ wlp,
               const float* __restrict__ blp, bf16* __restrict__ o)
{
  int flat = blockIdx.x * 4 + (threadIdx.x >> 6);  // (b*256+i)*4 + h
  int l = threadIdx.x & 63;
  int h = flat & 3, i = (flat >> 2) & 255, b = flat >> 10;
  const float wl = wlp[0], bl = blp[0];
  size_t rq = ((size_t)(b * 256 + i)) * 1536 + h * 128 + l;
  float q0 = __bfloat162float(qkv[rq]), q1 = __bfloat162float(qkv[rq + 64]);
  float att[9];
#pragma unroll
  for (int jj = 0; jj < 9; jj++) {
    int j = i - 4 + jj;
    float val = -1e30f;
    if (j >= 0 && j < 256) {
      size_t rk = ((size_t)(b * 256 + j)) * 1536 + h * 128 + l + 512;
      float p = q0 * __bfloat162float(qkv[rk]) + q1 * __bfloat162float(qkv[rk + 64]);
#pragma unroll
      for (int s = 32; s; s >>= 1) p += __shfl_xor(p, s);
      float dd = fabsf((float)(i - j));
      float adj = expf(-fabsf(wl * dd * dd - bl));
      val = p * 0.03125f + adj;   // 1/sqrt(1024)
    }
    att[jj] = val;
  }
  float m = att[0];
#pragma unroll
  for (int jj = 1; jj < 9; jj++) m = fmaxf(m, att[jj]);
  float p[9], sum = 0.f;
#pragma unroll
  for (int jj = 0; jj < 9; jj++) { p[jj] = expf(att[jj] - m); sum += p[jj]; }
  float inv = 1.f / sum;
  float o0 = 0.f, o1 = 0.f;
#pragma unroll
  for (int jj = 0; jj < 9; jj++) {
    int j = i - 4 + jj;
    if (j >= 0 && j < 256) {
      size_t rv = ((size_t)(b * 256 + j)) * 1536 + h * 128 + l + 1024;
      float wgt = p[jj] * inv;
      o0 += wgt * __bfloat162float(qkv[rv]);
      o1 += wgt * __bfloat162float(qkv[rv + 64]);
    }
  }
  size_t ro = ((size_t)(b * 256 + i)) * 512 + h * 128 + l;
  o[ro] = __float2bfloat16(o0);
  o[ro + 64] = __float2bfloat16(o1);
}

// ============ row norm + expmap0 -> Pb bf16, p0, alpha ============
__global__ __launch_bounds__(256)
void rownorm_proj(const float* __restrict__ xcat, const float* __restrict__ cx,
                  bf16* __restrict__ Pb, float* __restrict__ p0,
                  float* __restrict__ alpha)
{
  int row = blockIdx.x;
  int t = threadIdx.x;
  float4 e;
  if (t < 128) e = *(const float4*)&xcat[(size_t)row * 512 + t * 4];
  else         e = *(const float4*)&cx[(size_t)row * 512 + (t - 128) * 4];
  float s = e.x * e.x + e.y * e.y + e.z * e.z + e.w * e.w;
#pragma unroll
  for (int o = 32; o; o >>= 1) s += __shfl_xor(s, o);
  __shared__ float red[4];
  if ((t & 63) == 0) red[t >> 6] = s;
  __syncthreads();
  float tot = red[0] + red[1] + red[2] + red[3];
  float n = fmaxf(sqrtf(tot), 1e-7f);
  float ch = coshf(n), sh = sinhf(n);
  float sc = sh / n;
  float4 pr; pr.x = sc * e.x; pr.y = sc * e.y; pr.z = sc * e.z; pr.w = sc * e.w;
  size_t po = (size_t)row * 1024 + t * 4;
  Pb[po + 0] = __float2bfloat16(pr.x);
  Pb[po + 1] = __float2bfloat16(pr.y);
  Pb[po + 2] = __float2bfloat16(pr.z);
  Pb[po + 3] = __float2bfloat16(pr.w);
  float s2 = pr.x * pr.x + pr.y * pr.y + pr.z * pr.z + pr.w * pr.w;
#pragma unroll
  for (int o = 32; o; o >>= 1) s2 += __shfl_xor(s2, o);
  __syncthreads();
  if ((t & 63) == 0) red[t >> 6] = s2;
  __syncthreads();
  float tot2 = red[0] + red[1] + red[2] + red[3];
  if (t == 0) {
    float ns = fmaxf(sqrtf(tot2), 1e-7f);
    float y0 = fmaxf(ch, 1.f + 1e-7f);
    float d = logf(y0 + sqrtf(y0 * y0 - 1.f));
    p0[row] = ch;
    alpha[row] = d / ns;
  }
}

// ============ softmax(thr) + S@G1 + disadj@G2 (VALU f32) ============
// grid (T/32, B). 256 thr = 16 ty x 16 tx. rows r = ty*2+{0,1}; cols c = m*64+tx*4+q.
__global__ __launch_bounds__(256)
void adj_softmax_apply(const float* __restrict__ thr, const float* __restrict__ G,
                       const int* __restrict__ seq_len, float* __restrict__ xc)
{
  __shared__ float Sb[32][260];
  __shared__ float Bp[16][260];
  const int tid = threadIdx.x;
  const int ty = tid >> 4, tx = tid & 15;
  const int i0 = blockIdx.x * 32;
  const int b = blockIdx.y;
  const int sl = seq_len[b];

  // load thr rows
  float acc[2][16];
#pragma unroll
  for (int r = 0; r < 2; r++)
#pragma unroll
    for (int m = 0; m < 4; m++) {
      float4 t4 = *(const float4*)&thr[((size_t)(b * 256 + i0 + ty * 2 + r)) * 256 + m * 64 + tx * 4];
      acc[r][m*4+0] = t4.x; acc[r][m*4+1] = t4.y;
      acc[r][m*4+2] = t4.z; acc[r][m*4+3] = t4.w;
    }

  // masked softmax
  float mx[2] = {-1e30f, -1e30f};
#pragma unroll
  for (int r = 0; r < 2; r++)
#pragma unroll
    for (int m = 0; m < 4; m++)
#pragma unroll
      for (int q = 0; q < 4; q++) {
        int idx = m * 4 + q;
        int c = m * 64 + tx * 4 + q;
        float lg = (c < sl) ? acc[r][idx] : -1e30f;
        acc[r][idx] = lg;
        mx[r] = fmaxf(mx[r], lg);
      }
#pragma unroll
  for (int o = 1; o < 16; o <<= 1) {
    mx[0] = fmaxf(mx[0], __shfl_xor(mx[0], o));
    mx[1] = fmaxf(mx[1], __shfl_xor(mx[1], o));
  }
  float sm[2] = {0.f, 0.f};
#pragma unroll
  for (int r = 0; r < 2; r++)
#pragma unroll
    for (int idx = 0; idx < 16; idx++) {
      float e = (acc[r][idx] > -1e29f) ? expf(acc[r][idx] - mx[r]) : 0.f;
      acc[r][idx] = e; sm[r] += e;
    }
#pragma unroll
  for (int o = 1; o < 16; o <<= 1) {
    sm[0] += __shfl_xor(sm[0], o);
    sm[1] += __shfl_xor(sm[1], o);
  }
  float inv[2] = {1.f / sm[0], 1.f / sm[1]};
  bool vi[2] = { (i0 + ty * 2) < sl, (i0 + ty * 2 + 1) < sl };
#pragma unroll
  for (int r = 0; r < 2; r++)
#pragma unroll
    for (int m = 0; m < 4; m++) {
      float4 s4;
      s4.x = vi[r] ? acc[r][m*4+0] * inv[r] : 0.f;
      s4.y = vi[r] ? acc[r][m*4+1] * inv[r] : 0.f;
      s4.z = vi[r] ? acc[r][m*4+2] * inv[r] : 0.f;
      s4.w = vi[r] ? acc[r][m*4+3] * inv[r] : 0.f;
      *(float4*)&Sb[ty * 2 + r][m * 64 + tx * 4] = s4;
    }
  __syncthreads();

  // phase 2: x1 = leaky_relu(S @ G1)
  float acc2[2][16];
#pragma unroll
  for (int r = 0; r < 2; r++)
#pragma unroll
    for (int j = 0; j < 16; j++) acc2[r][j] = 0.f;

  for (int jt = 0; jt < 256; jt += 16) {
#pragma unroll
    for (int rep = 0; rep < 4; rep++) {
      int f = tid + rep * 256;
      int jl = f >> 6, c4 = (f & 63) << 2;
      *(float4*)&Bp[jl][c4] = *(const float4*)&G[(size_t)(b * 256 + jt + jl) * 512 + c4];
    }
    __syncthreads();
#pragma unroll
    for (int jj = 0; jj < 16; jj++) {
      float s0 = Sb[ty * 2][jt + jj];
      float s1 = Sb[ty * 2 + 1][jt + jj];
      float4 bm[4];
#pragma unroll
      for (int m = 0; m < 4; m++) bm[m] = *(const float4*)&Bp[jj][m * 64 + tx * 4];
#pragma unroll
      for (int m = 0; m < 4; m++) {
        acc2[0][m*4+0] = fmaf(s0, bm[m].x, acc2[0][m*4+0]);
        acc2[0][m*4+1] = fmaf(s0, bm[m].y, acc2[0][m*4+1]);
        acc2[0][m*4+2] = fmaf(s0, bm[m].z, acc2[0][m*4+2]);
        acc2[0][m*4+3] = fmaf(s0, bm[m].w, acc2[0][m*4+3]);
        acc2[1][m*4+0] = fmaf(s1, bm[m].x, acc2[1][m*4+0]);
        acc2[1][m*4+1] = fmaf(s1, bm[m].y, acc2[1][m*4+1]);
        acc2[1][m*4+2] = fmaf(s1, bm[m].z, acc2[1][m*4+2]);
        acc2[1][m*4+3] = fmaf(s1, bm[m].w, acc2[1][m*4+3]);
      }
    }
    __syncthreads();
  }
#pragma unroll
  for (int r = 0; r < 2; r++)
#pragma unroll
    for (int m = 0; m < 4; m++) {
      float4 o4;
      float v0 = acc2[r][m*4+0], v1 = acc2[r][m*4+1], v2 = acc2[r][m*4+2], v3 = acc2[r][m*4+3];
      o4.x = v0 > 0.f ? v0 : 0.01f * v0;
      o4.y = v1 > 0.f ? v1 : 0.01f * v1;
      o4.z = v2 > 0.f ? v2 : 0.01f * v2;
      o4.w = v3 > 0.f ? v3 : 0.01f * v3;
      *(float4*)&xc[(size_t)(b * 256 + i0 + ty * 2 + r) * 512 + m * 64 + tx * 4] = o4;
    }

  // phase 3: x2 = leaky_relu(disadj @ G2)
  const float INV_E = 0.36787944117144233f;
#pragma unroll
  for (int r = 0; r < 2; r++)
#pragma unroll
    for (int j = 0; j < 16; j++) acc2[r][j] = 0.f;

  for (int jt = 0; jt < 256; jt += 16) {
#pragma unroll
    for (int rep = 0; rep < 4; rep++) {
      int f = tid + rep * 256;
      int jl = f >> 6, c4 = (f & 63) << 2;
      *(float4*)&Bp[jl][c4] = *(const float4*)&G[(size_t)(b * 256 + jt + jl) * 512 + 256 + c4];
    }
    __syncthreads();
#pragma unroll
    for (int jj = 0; jj < 16; jj++) {
      int j = jt + jj;
      float d0 = expf(-fabsf((float)(i0 + ty * 2 - j)) * INV_E);
      float d1 = expf(-fabsf((float)(i0 + ty * 2 + 1 - j)) * INV_E);
      float4 bm[4];
#pragma unroll
      for (int m = 0; m < 4; m++) bm[m] = *(const float4*)&Bp[jj][m * 64 + tx * 4];
#pragma unroll
      for (int m = 0; m < 4; m++) {
        acc2[0][m*4+0] = fmaf(d0, bm[m].x, acc2[0][m*4+0]);
        acc2[0][m*4+1] = fmaf(d0, bm[m].y, acc2[0][m*4+1]);
        acc2[0][m*4+2] = fmaf(d0, bm[m].z, acc2[0][m*4+2]);
        acc2[0][m*4+3] = fmaf(d0, bm[m].w, acc2[0][m*4+3]);
        acc2[1][m*4+0] = fmaf(d1, bm[m].x, acc2[1][m*4+0]);
        acc2[1][m*4+1] = fmaf(d1, bm[m].y, acc2[1][m*4+1]);
        acc2[1][m*4+2] = fmaf(d1, bm[m].z, acc2[1][m*4+2]);
        acc2[1][m*4+3] = fmaf(d1, bm[m].w, acc2[1][m*4+3]);
      }
    }
    __syncthreads();
  }
#pragma unroll
  for (int r = 0; r < 2; r++)
#pragma unroll
    for (int m = 0; m < 4; m++) {
      float4 o4;
      float v0 = acc2[r][m*4+0], v1 = acc2[r][m*4+1], v2 = acc2[r][m*4+2], v3 = acc2[r][m*4+3];
      o4.x = v0 > 0.f ? v0 : 0.01f * v0;
      o4.y = v1 > 0.f ? v1 : 0.01f * v1;
      o4.z = v2 > 0.f ? v2 : 0.01f * v2;
      o4.w = v3 > 0.f ? v3 : 0.01f * v3;
      *(float4*)&xc[(size_t)(b * 256 + i0 + ty * 2 + r) * 512 + 256 + m * 64 + tx * 4] = o4;
    }
}

// ============ LayerNorm over 512, bf16 out ============
__global__ __launch_bounds__(256)
void layernorm_k(const float* __restrict__ xc, const float* __restrict__ g,
                 const float* __restrict__ bta, bf16* __restrict__ out)
{
  int row = blockIdx.x * 4 + (threadIdx.x >> 6);
  int l = threadIdx.x & 63;
  const float* r = xc + (size_t)row * 512;
  float v[8];
  float s = 0.f;
#pragma unroll
  for (int q = 0; q < 8; q++) { v[q] = r[l + 64 * q]; s += v[q]; }
#pragma unroll
  for (int o = 32; o; o >>= 1) s += __shfl_xor(s, o);
  float mu = s * (1.f / 512.f);
  float s2 = 0.f;
#pragma unroll
  for (int q = 0; q < 8; q++) { float d = v[q] - mu; s2 += d * d; }
#pragma unroll
  for (int o = 32; o; o >>= 1) s2 += __shfl_xor(s2, o);
  float var = s2 * (1.f / 512.f);
  float inv = 1.f / sqrtf(var + 1e-5f);
#pragma unroll
  for (int q = 0; q < 8; q++) {
    int c = l + 64 * q;
    out[(size_t)row * 512 + c] = __float2bfloat16((v[q] - mu) * inv * g[c] + bta[c]);
  }
}

// ============ x_e = sigmoid(xt @ Wcls + bcls) ============
__global__ __launch_bounds__(256)
void xe_kernel(const float* __restrict__ xt, const float* __restrict__ Wcls,
               const float* __restrict__ bcls, float* __restrict__ out)
{
  int row = blockIdx.x * 4 + (threadIdx.x >> 6);
  int l = threadIdx.x & 63;
  float s = 0.f;
#pragma unroll
  for (int q = 0; q < 8; q++) {
    int c = l + 64 * q;
    s += xt[(size_t)row * 512 + c] * Wcls[c];
  }
#pragma unroll
  for (int o = 32; o; o >>= 1) s += __shfl_xor(s, o);
  if (l == 0) out[row] = 1.f / (1.f + expf(-(s + bcls[0])));
}

// ============ transpose xt (B,T,512) -> (B,512,T) ============
__global__ void transpose_xt(const float* __restrict__ xt, float* __restrict__ out)
{
  __shared__ float tile[32][33];
  int b = blockIdx.z;
  int t0 = blockIdx.x * 32, d0 = blockIdx.y * 32;
  int tx = threadIdx.x, ty = threadIdx.y;   // 32 x 8
#pragma unroll
  for (int i = 0; i < 4; i++)
    tile[ty + i * 8][tx] = xt[((size_t)(b * 256) + t0 + ty + i * 8) * 512 + d0 + tx];
  __syncthreads();
#pragma unroll
  for (int i = 0; i < 4; i++)
    out[((size_t)(b * 512) + d0 + ty + i * 8) * 256 + t0 + tx] = tile[tx][ty + i * 8];
}

// ============ launch ============
extern "C" void kernel_launch(void* const* d_in, const int* in_sizes, int n_in,
                              void* d_out, int out_size, void* d_ws, size_t ws_size,
                              hipStream_t stream) {
  (void)in_sizes; (void)n_in; (void)out_size; (void)ws_size;
  const float* x     = (const float*)d_in[0];
  const float* c_x   = (const float*)d_in[1];
  const float* w_loc = (const float*)d_in[2];
  const float* b_loc = (const float*)d_in[3];
  const float* Wq    = (const float*)d_in[4];
  const float* bq    = (const float*)d_in[5];
  const float* Wk    = (const float*)d_in[6];
  const float* bk    = (const float*)d_in[7];
  const float* Wv    = (const float*)d_in[8];
  const float* bv    = (const float*)d_in[9];
  const float* Wo    = (const float*)d_in[10];
  const float* bo    = (const float*)d_in[11];
  const float* Wc1   = (const float*)d_in[12];
  const float* bc1   = (const float*)d_in[13];
  const float* Wg1   = (const float*)d_in[14];
  const float* bg1   = (const float*)d_in[15];
  const float* Wg2   = (const float*)d_in[16];
  const float* bg2   = (const float*)d_in[17];
  const float* ln_g  = (const float*)d_in[18];
  const float* ln_b  = (const float*)d_in[19];
  const float* Wl1   = (const float*)d_in[20];
  const float* bl1   = (const float*)d_in[21];
  const float* Wcls  = (const float*)d_in[22];
  const float* bcls  = (const float*)d_in[23];
  const int*   seq_len = (const int*)d_in[24];

  float* ws = (float*)d_ws;
  // region A [0, 8388608): xb -> x2b -> G1G2(f32) -> xnb   (bf16 regions use 2 elems/float slot)
  bf16*  xb    = (bf16*)ws;                       // 16384x1024 bf16
  bf16*  x2b   = (bf16*)ws;                       // 16384x1024 bf16
  float* G1G2  = ws;                              // 16384x512 f32
  bf16*  xnb   = (bf16*)ws;                       // 16384x512 bf16
  // region B [8388608, 25165824): qkvb -> (xcat, Pb)
  bf16*  qkvb  = (bf16*)(ws + 8388608);           // 16384x1536 bf16
  float* xcat  = ws + 8388608;                    // 16384x512 f32
  bf16*  Pb    = (bf16*)(ws + 16777216);          // 16384x1024 bf16
  // region C [25165824, 33554432): thr -> xt
  float* thr   = ws + 25165824;                   // 64x256x256 f32
  float* xt    = ws + 25165824;                   // 16384x512 f32
  // region E [33554432, 37748736): ob
  bf16*  ob    = (bf16*)(ws + 33554432);          // 16384x512 bf16
  // region F [37748736, 46137344): xc
  float* xc    = ws + 37748736;                   // 16384x512 f32
  // region G [46137344, ...): weights + scalars
  bf16*  WqkvT = (bf16*)(ws + 46137344);          // 1536x1024
  bf16*  WoT   = (bf16*)(ws + 46923776);          // 1024x512
  bf16*  Wc1T  = (bf16*)(ws + 47185920);          // 512x1024
  bf16*  Wg12T = (bf16*)(ws + 47448064);          // 512x1024
  bf16*  Wl1T  = (bf16*)(ws + 47710208);          // 512x512
  float* bqkv  = ws + 47841280;                   // 1536
  float* bgg   = ws + 47842816;                   // 512
  float* p0    = ws + 47843328;                   // 16384
  float* alpha = ws + 47859712;                   // 16384

  dim3 blk(256);
  dim3 tblk(32, 8);
  // weight packs (bf16, transposed to NT layout)
  transK<<<dim3(16, 32), tblk, 0, stream>>>(Wq,  WqkvT, 512,    0, 1024);
  transK<<<dim3(16, 32), tblk, 0, stream>>>(Wk,  WqkvT, 512,  512, 1024);
  transK<<<dim3(16, 32), tblk, 0, stream>>>(Wv,  WqkvT, 512, 1024, 1024);
  transK<<<dim3(32, 16), tblk, 0, stream>>>(Wo,  WoT, 1024,    0,  512);
  transK<<<dim3(16, 32), tblk, 0, stream>>>(Wc1, Wc1T, 512,    0, 1024);
  transK<<<dim3( 8, 32), tblk, 0, stream>>>(Wg1, Wg12T, 256,   0, 1024);
  transK<<<dim3( 8, 32), tblk, 0, stream>>>(Wg2, Wg12T, 256, 256, 1024);
  transK<<<dim3(16, 16), tblk, 0, stream>>>(Wl1, Wl1T, 512,    0,  512);
  conv_x<<<2048, blk, 0, stream>>>(x, xb, 4194304);
  pack_bias<<<8, blk, 0, stream>>>(bq, bk, bv, bg1, bg2, bqkv, bgg);

  // qkv = x @ [Wq|Wk|Wv] + b  (bf16 out, packed N=1536)
  gemm_nt<M_NONE, 1><<<dim3(12, 128), blk, 0, stream>>>(xb, WqkvT, bqkv, nullptr, nullptr, qkvb, 1024, 1536, 0);
  // banded attention
  band_attn<<<16384, blk, 0, stream>>>(qkvb, w_loc, b_loc, ob);
  // x2 = x + o@Wo + bo (bf16 out)
  gemm_nt<M_RESID, 1><<<dim3(8, 128), blk, 0, stream>>>(ob, WoT, bo, x, nullptr, x2b, 512, 1024, 1024);
  // xcat = relu(x2@Wc1 + bc1) (f32 out)
  gemm_nt<M_RELU, 0><<<dim3(4, 128), blk, 0, stream>>>(x2b, Wc1T, bc1, nullptr, xcat, nullptr, 1024, 512, 0);
  // expmap0 -> Pb bf16, p0, alpha
  rownorm_proj<<<16384, blk, 0, stream>>>(xcat, c_x, Pb, p0, alpha);
  // G = alpha*(Pb@[Wg1|Wg2]) + b (f32 out)
  gemm_nt<M_ROWSCALE, 0><<<dim3(4, 128), blk, 0, stream>>>(Pb, Wg12T, bgg, alpha, G1G2, nullptr, 1024, 512, 0);
  // thr = lorentz threshold of P@P^T (MFMA batched)
  gemm_pp<<<dim3(2, 2, 64), blk, 0, stream>>>(Pb, p0, thr);
  // softmax + S@G1 + disadj@G2
  adj_softmax_apply<<<dim3(8, 64), blk, 0, stream>>>(thr, G1G2, seq_len, xc);
  // LayerNorm (bf16 out)
  layernorm_k<<<4096, blk, 0, stream>>>(xc, ln_g, ln_b, xnb);
  // xt = gelu(xn@Wl1 + bl1) (f32 out)
  gemm_nt<M_GELU, 0><<<dim3(4, 128), blk, 0, stream>>>(xnb, Wl1T, bl1, nullptr, xt, nullptr, 512, 512, 0);
  // outputs
  float* out = (float*)d_out;
  xe_kernel<<<4096, blk, 0, stream>>>(xt, Wcls, bcls, out);
  transpose_xt<<<dim3(8, 16, 64), tblk, 0, stream>>>(xt, out + 16384);
}